// Round 7
// baseline (1414.329 us; speedup 1.0000x reference)
//
#include <hip/hip_runtime.h>
#include <hip/hip_bf16.h>
#include <stdint.h>

// SelfAttention: out = softmax((x Wq^T)(x Wk^T)^T / sqrt(D)) (x Wv^T)
// SEQ=8192, D=1024, fp32 in/out. All GEMMs bf16 MFMA (absmax ~2.4e-4).
// R16 = R9 kernel (best measured: S-GEMM 203us @ 3 blocks/CU) with ONE
// change: __launch_bounds__(256,3) -> (256,5). Evidence from R9-R15:
//  - schedules (2ph/coarse/8ph/min-sync), tile 128/256, direct-B: all
//    203-342us; every pipe pinned at 26-29% (MFMA/VALU/LDS/HBM).
//  - OccupancyPercent tracks blocks/CU exactly; R9's 3 blocks/CU is the
//    best config. Per-block tile wall ~5.7k cyc vs 1.86k MFMA work: each
//    block stalls on its own DMA drain; overlap comes from CO-RESIDENT
//    BLOCKS (m114), not intra-block scheduling.
//  => concurrency-limited. 32KB LDS/block allows 5 blocks/CU (160KB).
// Keeps R8/R9: BK=64, row-rotation LDS swizzle (0 conflicts), GROUP_M=8 L2
// swizzle, compact q/k/v de-interleave, fused softmax epilogues (MODE1
// exp2 + atomic row sums, MODE2 1/l), split-K=2 PV.
//
// Workspace (~230 MB): x_bf16 16 | Wcat 6 | q 16 | k 16 | v 16 | S 128 | pv 32
//                      | lsum 32KB

#define SEQ 8192
#define DMODEL 1024
#define LOG2E 1.44269504088896340736f
#define GROUP_M 8

typedef __bf16 bf16_t;
typedef __bf16 bf16x8 __attribute__((ext_vector_type(8)));
typedef float f32x4 __attribute__((ext_vector_type(4)));

// ---------------- fp32 -> bf16 convert ----------------
__global__ __launch_bounds__(256)
void convert_f32_bf16(const float* __restrict__ in, bf16_t* __restrict__ out, long n) {
    long i = ((long)blockIdx.x * 256 + threadIdx.x) * 4;
    if (i + 3 < n) {
        const float4 v = *(const float4*)(in + i);
        union { ushort4 u; bf16_t b[4]; } p;
        p.b[0] = (bf16_t)v.x; p.b[1] = (bf16_t)v.y;
        p.b[2] = (bf16_t)v.z; p.b[3] = (bf16_t)v.w;
        *(ushort4*)(out + i) = p.u;
    }
}

// ---------------- fp32 add: out += part ----------------
__global__ __launch_bounds__(256)
void add_f32(float* __restrict__ out, const float* __restrict__ part, long n) {
    long i = ((long)blockIdx.x * 256 + threadIdx.x) * 4;
    if (i + 3 < n) {
        float4 a = *(const float4*)(out + i);
        const float4 b = *(const float4*)(part + i);
        a.x += b.x; a.y += b.y; a.z += b.z; a.w += b.w;
        *(float4*)(out + i) = a;
    }
}

// ---------------- zero fp32 buffer ----------------
__global__ __launch_bounds__(256)
void zero_f32(float* __restrict__ p, int n) {
    int i = blockIdx.x * 256 + threadIdx.x;
    if (i < n) p[i] = 0.0f;
}

// ---------------- NT GEMM: C[M,N] = A[M,K] @ B[N,K]^T ----------------
// 128x128 tile, BK=64, 256 threads (4 waves, 2x2), each wave 64x64 via 4x4
// grid of mfma_f32_16x16x32_bf16, two K=32 steps per staged tile.
// global_load_lds width-16 staging + row-rotation swizzle (0 bank conflicts).
// Grouped swizzle (GROUP_M row-tiles, col-major inside) for L2/L3 locality.
// Split-K via grid.x = nsplit*nbm*nbn. De-interleave epilogue via plane/cshift.
// MODE 0: C = alpha*acc.
// MODE 1: C = exp2(alpha*acc) (bf16), atomic row-sums into lsum.
// MODE 2: C = acc / lsum[row]  (softmax normalization folded into PV).
// launch_bounds(256,5): 5 blocks/CU target (32KB LDS x5 = 160KB exact);
// cross-block TLP is the only lever that moved counters (R9-R15 record).
template <typename OutT, int MODE>
__global__ __launch_bounds__(256, 5)
void gemm_nt(const bf16_t* __restrict__ A, const bf16_t* __restrict__ B,
             OutT* __restrict__ C0, OutT* __restrict__ C1,
             float* __restrict__ lsum,
             int M, int N, int Kps, int lda, int ldb, int ldc,
             long plane, int cshift, float alpha)
{
    __shared__ bf16_t As[128 * 64];
    __shared__ bf16_t Bs[128 * 64];

    const int tid  = threadIdx.x;
    const int wave = tid >> 6;
    const int lane = tid & 63;

    const int nbm = M >> 7, nbn = N >> 7;
    const int tiles = nbm * nbn;
    int bid = blockIdx.x;
    const int sid = bid / tiles;        // split-K id
    bid -= sid * tiles;
    const long kbase = (long)sid * Kps;
    OutT* __restrict__ C = sid ? C1 : C0;

    // grouped swizzle
    const int per_group = GROUP_M * nbn;
    const int gid   = bid / per_group;
    const int rem   = bid - gid * per_group;
    const int first = gid * GROUP_M;
    const int gsz   = min(nbm - first, GROUP_M);
    const int bm    = first + rem % gsz;
    const int bn    = rem / gsz;
    const long row0 = (long)bm * 128;
    const long col0 = (long)bn * 128;

    const int wm = (wave >> 1) * 64;   // wave's 64x64 sub-tile
    const int wn = (wave & 1) * 64;
    const int lr = lane & 15;          // fragment non-K index
    const int lq = lane >> 4;          // quad 0..3 -> k-chunk / row group

    f32x4 acc[4][4] = {};

    for (int k0 = 0; k0 < Kps; k0 += 64) {
        // Stage A,B 128x64 tiles: 1024 chunks of 16B; row r=c>>3, physical
        // slot p=c&7 holds global chunk (p+r)&7 (rotation within the 128B row;
        // coalescing unchanged, b128 reads 2 lanes/bank = free).
        #pragma unroll
        for (int i = 0; i < 4; ++i) {
            const int c = i * 256 + wave * 64 + lane;
            const int r = c >> 3, p = c & 7;
            const int l = (p + r) & 7;
            const bf16_t* ga = A + (row0 + r) * (long)lda + kbase + k0 + l * 8;
            const bf16_t* gb = B + (col0 + r) * (long)ldb + kbase + k0 + l * 8;
            __builtin_amdgcn_global_load_lds(
                (const __attribute__((address_space(1))) uint32_t*)ga,
                (__attribute__((address_space(3))) uint32_t*)(As + (long)c * 8),
                16, 0, 0);
            __builtin_amdgcn_global_load_lds(
                (const __attribute__((address_space(1))) uint32_t*)gb,
                (__attribute__((address_space(3))) uint32_t*)(Bs + (long)c * 8),
                16, 0, 0);
        }
        __syncthreads();

        #pragma unroll
        for (int t = 0; t < 2; ++t) {   // two K=32 MFMA steps per staged tile
            bf16x8 af[4], bfr[4];
            #pragma unroll
            for (int mi = 0; mi < 4; ++mi) {
                const int r = wm + mi * 16 + lr;
                const int p = (t * 4 + lq - r) & 7;
                af[mi] = *(const bf16x8*)(As + (long)r * 64 + p * 8);
            }
            #pragma unroll
            for (int ni = 0; ni < 4; ++ni) {
                const int r = wn + ni * 16 + lr;
                const int p = (t * 4 + lq - r) & 7;
                bfr[ni] = *(const bf16x8*)(Bs + (long)r * 64 + p * 8);
            }
            #pragma unroll
            for (int mi = 0; mi < 4; ++mi)
                #pragma unroll
                for (int ni = 0; ni < 4; ++ni)
                    acc[mi][ni] = __builtin_amdgcn_mfma_f32_16x16x32_bf16(
                        af[mi], bfr[ni], acc[mi][ni], 0, 0, 0);
        }
        __syncthreads();
    }

    // Epilogue: C/D layout col=lane&15, row=(lane>>4)*4+reg  [m89/m91 verified]
    OutT* __restrict__ Cb = C + (col0 >> cshift) * plane;
    const int ccol0 = (int)(col0 & (((long)1 << cshift) - 1));

    if (MODE == 1) {
        // P' = exp2(alpha*acc); row partial sums -> shfl over lr -> atomicAdd.
        #pragma unroll
        for (int mi = 0; mi < 4; ++mi)
            #pragma unroll
            for (int rg = 0; rg < 4; ++rg) {
                const long r = row0 + wm + mi * 16 + lq * 4 + rg;
                float part = 0.f;
                #pragma unroll
                for (int ni = 0; ni < 4; ++ni) {
                    const int c = ccol0 + wn + ni * 16 + lr;
                    const float e = exp2f(alpha * acc[mi][ni][rg]);
                    part += e;
                    Cb[r * (long)ldc + c] = (OutT)e;
                }
                part += __shfl_xor(part, 1);
                part += __shfl_xor(part, 2);
                part += __shfl_xor(part, 4);
                part += __shfl_xor(part, 8);
                if (lr == 0) atomicAdd(&lsum[r], part);
            }
    } else if (MODE == 2) {
        #pragma unroll
        for (int mi = 0; mi < 4; ++mi)
            #pragma unroll
            for (int rg = 0; rg < 4; ++rg) {
                const long r = row0 + wm + mi * 16 + lq * 4 + rg;
                const float inv = 1.0f / lsum[r];
                #pragma unroll
                for (int ni = 0; ni < 4; ++ni) {
                    const int c = ccol0 + wn + ni * 16 + lr;
                    Cb[r * (long)ldc + c] = (OutT)(acc[mi][ni][rg] * inv);
                }
            }
    } else {
        #pragma unroll
        for (int mi = 0; mi < 4; ++mi)
            #pragma unroll
            for (int ni = 0; ni < 4; ++ni)
                #pragma unroll
                for (int rg = 0; rg < 4; ++rg) {
                    const long r = row0 + wm + mi * 16 + lq * 4 + rg;
                    const int  c = ccol0 + wn + ni * 16 + lr;
                    Cb[r * (long)ldc + c] = (OutT)(alpha * acc[mi][ni][rg]);
                }
    }
}

// ---------------- bf16 transpose (strided in), v -> v^T ----------------
__global__ __launch_bounds__(256)
void transpose_bf16(const bf16_t* __restrict__ in, bf16_t* __restrict__ out,
                    int R, int ldin, int ldout)
{
    __shared__ bf16_t tile[32][33];
    const int tx = threadIdx.x & 31;
    const int ty = threadIdx.x >> 5;   // 0..7
    const int c0 = blockIdx.x * 32;
    const int r0 = blockIdx.y * 32;
    #pragma unroll
    for (int j = 0; j < 32; j += 8)
        tile[ty + j][tx] = in[(long)(r0 + ty + j) * ldin + c0 + tx];
    __syncthreads();
    #pragma unroll
    for (int j = 0; j < 32; j += 8)
        out[(long)(c0 + ty + j) * ldout + r0 + tx] = tile[tx][ty + j];
}

extern "C" void kernel_launch(void* const* d_in, const int* in_sizes, int n_in,
                              void* d_out, int out_size, void* d_ws, size_t ws_size,
                              hipStream_t stream)
{
    const float* x  = (const float*)d_in[0];
    const float* Wq = (const float*)d_in[1];
    const float* Wk = (const float*)d_in[2];
    const float* Wv = (const float*)d_in[3];
    float* out = (float*)d_out;

    char* ws = (char*)d_ws;
    const long XN = (long)SEQ * DMODEL;     // 8,388,608
    const long WN = (long)DMODEL * DMODEL;  // 1,048,576
    const long SN = (long)SEQ * SEQ;        // 67,108,864

    bf16_t* xb   = (bf16_t*)ws;                              // 16MB
    bf16_t* wcat = (bf16_t*)(ws + XN * 2);                   // 6MB [3072,1024]
    bf16_t* qb   = (bf16_t*)(ws + XN * 2 + WN * 6);          // 16MB compact
    bf16_t* kb   = qb + XN;                                  // 16MB compact
    bf16_t* vb   = qb + 2 * XN;                              // 16MB compact
    bf16_t* Sb   = (bf16_t*)(ws + XN * 2 + WN * 6 + XN * 6); // 128MB
    float*  pvp  = (float*)(ws + XN * 2 + WN * 6 + XN * 6 + SN * 2); // 32MB
    float*  lsum = (float*)(ws + XN * 2 + WN * 6 + XN * 6 + SN * 2 + XN * 4); // 32KB
    bf16_t* vtb  = xb;  // v^T overlays x_bf16 (x dead after QKV GEMM)

    const size_t base_need = (size_t)(XN * 2 + WN * 6 + XN * 6 + SN * 2);
    const bool use_split = ws_size >= base_need + XN * 4 + SEQ * 4;
    if (!use_split) lsum = (float*)(ws + base_need);  // reuse pvp slot

    convert_f32_bf16<<<(int)(XN / 4 / 256), 256, 0, stream>>>(x,  xb, XN);
    convert_f32_bf16<<<(int)(WN / 4 / 256), 256, 0, stream>>>(Wq, wcat,          WN);
    convert_f32_bf16<<<(int)(WN / 4 / 256), 256, 0, stream>>>(Wk, wcat + WN,     WN);
    convert_f32_bf16<<<(int)(WN / 4 / 256), 256, 0, stream>>>(Wv, wcat + 2 * WN, WN);
    zero_f32<<<SEQ / 256, 256, 0, stream>>>(lsum, SEQ);

    dim3 blk(256);
    // qkv = x @ Wcat^T, de-interleaved into compact q|k|v (plane=XN, cshift=10)
    gemm_nt<bf16_t, 0><<<(SEQ / 128) * (3 * DMODEL / 128), blk, 0, stream>>>(
        xb, wcat, qb, qb, nullptr, SEQ, 3 * DMODEL, DMODEL,
        DMODEL, DMODEL, DMODEL, XN, 10, 1.0f);

    // v^T for the PV GEMM (writes over dead x_bf16)
    transpose_bf16<<<dim3(DMODEL / 32, SEQ / 32), blk, 0, stream>>>(
        vb, vtb, SEQ, DMODEL, SEQ);

    // P' = exp2((q@k^T) * scale * log2e), bf16; row sums -> lsum (atomic)
    gemm_nt<bf16_t, 1><<<(SEQ / 128) * (SEQ / 128), blk, 0, stream>>>(
        qb, kb, Sb, Sb, lsum, SEQ, SEQ, DMODEL,
        DMODEL, DMODEL, SEQ, 0, 30, 0.03125f * LOG2E);

    // out = (P' @ v) / l  (PV epilogue applies 1/lsum[row]). Split-K=2 if ws.
    if (use_split) {
        gemm_nt<float, 2><<<2 * (SEQ / 128) * (DMODEL / 128), blk, 0, stream>>>(
            Sb, vtb, out, pvp, lsum, SEQ, DMODEL, SEQ / 2,
            SEQ, SEQ, DMODEL, 0, 30, 1.0f);
        add_f32<<<(int)(XN / 4 / 256), 256, 0, stream>>>(out, pvp, XN);
    } else {
        gemm_nt<float, 2><<<(SEQ / 128) * (DMODEL / 128), blk, 0, stream>>>(
            Sb, vtb, out, out, lsum, SEQ, DMODEL, SEQ,
            SEQ, SEQ, DMODEL, 0, 30, 1.0f);
    }
}

// Round 8
// 502.968 us; speedup vs baseline: 2.8120x; 2.8120x over previous
//
#include <hip/hip_runtime.h>
#include <hip/hip_bf16.h>
#include <stdint.h>

// SelfAttention: out = softmax((x Wq^T)(x Wk^T)^T / sqrt(D)) (x Wv^T)
// SEQ=8192, D=1024, fp32 in/out. All GEMMs bf16 MFMA (absmax ~2.4e-4).
// R17 = R9 structure with BK 64->32 (LDS 32KB->16KB per block) + XCD swizzle.
// Evidence: R9's 3 blocks/CU is the best measured config; identical m97
// structure also pins at ~3 blocks/CU (m114) -> LDS-capped. R16 (force via
// launch_bounds(,5)) spilled acc (VGPR 48, 1GB scratch). Clean lever: shrink
// LDS; 16KB/block -> wave-slot cap 8 blocks/CU, VGPR untouched (~60).
// More co-resident blocks cover each other's staging stalls (m114 TLP).
// BK=32 bank math: physical slot p holds global chunk (p+(r>>2))&3; reads
// use p0=(lq-((lr>>2)&3))&3 -> ds_read_b128 is bank-optimal (8 lanes per
// 4-bank window, distinct rows); staging source perm is thread-constant.
// XCD swizzle (T1, bijective: all tile-counts %8==0) ahead of GROUP_M.
// Keeps: compact q/k/v de-interleave, fused softmax epilogues (MODE1
// exp2 + atomic row sums, MODE2 1/l), split-K=2 PV.
//
// Workspace (~230 MB): x_bf16 16 | Wcat 6 | q 16 | k 16 | v 16 | S 128 | pv 32
//                      | lsum 32KB

#define SEQ 8192
#define DMODEL 1024
#define LOG2E 1.44269504088896340736f
#define GROUP_M 8

typedef __bf16 bf16_t;
typedef __bf16 bf16x8 __attribute__((ext_vector_type(8)));
typedef float f32x4 __attribute__((ext_vector_type(4)));

// ---------------- fp32 -> bf16 convert ----------------
__global__ __launch_bounds__(256)
void convert_f32_bf16(const float* __restrict__ in, bf16_t* __restrict__ out, long n) {
    long i = ((long)blockIdx.x * 256 + threadIdx.x) * 4;
    if (i + 3 < n) {
        const float4 v = *(const float4*)(in + i);
        union { ushort4 u; bf16_t b[4]; } p;
        p.b[0] = (bf16_t)v.x; p.b[1] = (bf16_t)v.y;
        p.b[2] = (bf16_t)v.z; p.b[3] = (bf16_t)v.w;
        *(ushort4*)(out + i) = p.u;
    }
}

// ---------------- fp32 add: out += part ----------------
__global__ __launch_bounds__(256)
void add_f32(float* __restrict__ out, const float* __restrict__ part, long n) {
    long i = ((long)blockIdx.x * 256 + threadIdx.x) * 4;
    if (i + 3 < n) {
        float4 a = *(const float4*)(out + i);
        const float4 b = *(const float4*)(part + i);
        a.x += b.x; a.y += b.y; a.z += b.z; a.w += b.w;
        *(float4*)(out + i) = a;
    }
}

// ---------------- zero fp32 buffer ----------------
__global__ __launch_bounds__(256)
void zero_f32(float* __restrict__ p, int n) {
    int i = blockIdx.x * 256 + threadIdx.x;
    if (i < n) p[i] = 0.0f;
}

// ---------------- NT GEMM: C[M,N] = A[M,K] @ B[N,K]^T ----------------
// 128x128 tile, BK=32, 256 threads (4 waves, 2x2), each wave 64x64 via 4x4
// grid of mfma_f32_16x16x32_bf16, ONE K=32 step per staged tile.
// global_load_lds width-16 staging + (r>>2)-rotation swizzle (bank-optimal).
// XCD-chunked bid, then grouped swizzle (GROUP_M) for L2/L3 locality.
// Split-K via grid.x = nsplit*nbm*nbn. De-interleave epilogue via plane/cshift.
// MODE 0: C = alpha*acc.
// MODE 1: C = exp2(alpha*acc) (bf16), atomic row-sums into lsum.
// MODE 2: C = acc / lsum[row]  (softmax normalization folded into PV).
template <typename OutT, int MODE>
__global__ __launch_bounds__(256, 3)
void gemm_nt(const bf16_t* __restrict__ A, const bf16_t* __restrict__ B,
             OutT* __restrict__ C0, OutT* __restrict__ C1,
             float* __restrict__ lsum,
             int M, int N, int Kps, int lda, int ldb, int ldc,
             long plane, int cshift, float alpha)
{
    __shared__ bf16_t As[128 * 32];   // 8KB
    __shared__ bf16_t Bs[128 * 32];   // 8KB

    const int tid  = threadIdx.x;
    const int wave = tid >> 6;
    const int lane = tid & 63;

    const int nbm = M >> 7, nbn = N >> 7;
    const int tiles = nbm * nbn;
    int bid = blockIdx.x;
    const int sid = bid / tiles;        // split-K id
    bid -= sid * tiles;
    const long kbase = (long)sid * Kps;
    OutT* __restrict__ C = sid ? C1 : C0;

    // XCD-chunked swizzle (bijective: tiles % 8 == 0 for all our launches):
    // consecutive hardware dispatches (same XCD) get contiguous tile ranges.
    const int cpx = tiles >> 3;
    bid = (bid & 7) * cpx + (bid >> 3);

    // grouped swizzle (GROUP_M row-tiles, col-major inside)
    const int per_group = GROUP_M * nbn;
    const int gid   = bid / per_group;
    const int rem   = bid - gid * per_group;
    const int first = gid * GROUP_M;
    const int gsz   = min(nbm - first, GROUP_M);
    const int bm    = first + rem % gsz;
    const int bn    = rem / gsz;
    const long row0 = (long)bm * 128;
    const long col0 = (long)bn * 128;

    const int wm = (wave >> 1) * 64;   // wave's 64x64 sub-tile
    const int wn = (wave & 1) * 64;
    const int lr = lane & 15;          // fragment non-K index
    const int lq = lane >> 4;          // k-chunk (K=32: chunk lq = k lq*8..+8)

    // --- staging: tile = 512 chunks of 16B; chunk c = i*256+tid (i=0,1);
    // row r=c>>2, phys slot p=c&3 holds global chunk l=(p+(r>>2))&3.
    // l is thread-constant: l = ((tid&3) + ((tid>>4)&3)) & 3.
    const int rt = tid >> 2;                         // row within 64-row block
    const int sl = ((tid & 3) + ((tid >> 4) & 3)) & 3;
    const bf16_t* pa = A + (row0 + rt) * (long)lda + kbase + sl * 8;
    const bf16_t* pb = B + (col0 + rt) * (long)ldb + kbase + sl * 8;

    // --- LDS read slot: want chunk g=lq at row r: p0=(lq-((r>>2)&3))&3;
    // (r>>2)&3 == (lr>>2)&3 for all mi/ni (wm, mi*16 are mult of 16).
    const int p0  = (lq - ((lr >> 2) & 3)) & 3;
    const int oA  = (wm + lr) * 32 + p0 * 8;
    const int oB  = (wn + lr) * 32 + p0 * 8;

    f32x4 acc[4][4] = {};

    for (int k0 = 0; k0 < Kps; k0 += 32) {
        // Stage A,B 128x32 tiles: 2 x 1KB wave-chunks each per thread pair.
        #pragma unroll
        for (int i = 0; i < 2; ++i) {
            const bf16_t* ga = pa + k0 + (long)i * 64 * lda;
            const bf16_t* gb = pb + k0 + (long)i * 64 * ldb;
            __builtin_amdgcn_global_load_lds(
                (const __attribute__((address_space(1))) uint32_t*)ga,
                (__attribute__((address_space(3))) uint32_t*)(As + (long)(i * 256 + tid) * 8),
                16, 0, 0);
            __builtin_amdgcn_global_load_lds(
                (const __attribute__((address_space(1))) uint32_t*)gb,
                (__attribute__((address_space(3))) uint32_t*)(Bs + (long)(i * 256 + tid) * 8),
                16, 0, 0);
        }
        __syncthreads();

        bf16x8 af[4], bfr[4];
        #pragma unroll
        for (int mi = 0; mi < 4; ++mi)
            af[mi] = *(const bf16x8*)(As + oA + mi * 512);
        #pragma unroll
        for (int ni = 0; ni < 4; ++ni)
            bfr[ni] = *(const bf16x8*)(Bs + oB + ni * 512);
        #pragma unroll
        for (int mi = 0; mi < 4; ++mi)
            #pragma unroll
            for (int ni = 0; ni < 4; ++ni)
                acc[mi][ni] = __builtin_amdgcn_mfma_f32_16x16x32_bf16(
                    af[mi], bfr[ni], acc[mi][ni], 0, 0, 0);
        __syncthreads();
    }

    // Epilogue: C/D layout col=lane&15, row=(lane>>4)*4+reg  [m89/m91 verified]
    OutT* __restrict__ Cb = C + (col0 >> cshift) * plane;
    const int ccol0 = (int)(col0 & (((long)1 << cshift) - 1));

    if (MODE == 1) {
        // P' = exp2(alpha*acc); row partial sums -> shfl over lr -> atomicAdd.
        #pragma unroll
        for (int mi = 0; mi < 4; ++mi)
            #pragma unroll
            for (int rg = 0; rg < 4; ++rg) {
                const long r = row0 + wm + mi * 16 + lq * 4 + rg;
                float part = 0.f;
                #pragma unroll
                for (int ni = 0; ni < 4; ++ni) {
                    const int c = ccol0 + wn + ni * 16 + lr;
                    const float e = exp2f(alpha * acc[mi][ni][rg]);
                    part += e;
                    Cb[r * (long)ldc + c] = (OutT)e;
                }
                part += __shfl_xor(part, 1);
                part += __shfl_xor(part, 2);
                part += __shfl_xor(part, 4);
                part += __shfl_xor(part, 8);
                if (lr == 0) atomicAdd(&lsum[r], part);
            }
    } else if (MODE == 2) {
        #pragma unroll
        for (int mi = 0; mi < 4; ++mi)
            #pragma unroll
            for (int rg = 0; rg < 4; ++rg) {
                const long r = row0 + wm + mi * 16 + lq * 4 + rg;
                const float inv = 1.0f / lsum[r];
                #pragma unroll
                for (int ni = 0; ni < 4; ++ni) {
                    const int c = ccol0 + wn + ni * 16 + lr;
                    Cb[r * (long)ldc + c] = (OutT)(acc[mi][ni][rg] * inv);
                }
            }
    } else {
        #pragma unroll
        for (int mi = 0; mi < 4; ++mi)
            #pragma unroll
            for (int ni = 0; ni < 4; ++ni)
                #pragma unroll
                for (int rg = 0; rg < 4; ++rg) {
                    const long r = row0 + wm + mi * 16 + lq * 4 + rg;
                    const int  c = ccol0 + wn + ni * 16 + lr;
                    Cb[r * (long)ldc + c] = (OutT)(alpha * acc[mi][ni][rg]);
                }
    }
}

// ---------------- bf16 transpose (strided in), v -> v^T ----------------
__global__ __launch_bounds__(256)
void transpose_bf16(const bf16_t* __restrict__ in, bf16_t* __restrict__ out,
                    int R, int ldin, int ldout)
{
    __shared__ bf16_t tile[32][33];
    const int tx = threadIdx.x & 31;
    const int ty = threadIdx.x >> 5;   // 0..7
    const int c0 = blockIdx.x * 32;
    const int r0 = blockIdx.y * 32;
    #pragma unroll
    for (int j = 0; j < 32; j += 8)
        tile[ty + j][tx] = in[(long)(r0 + ty + j) * ldin + c0 + tx];
    __syncthreads();
    #pragma unroll
    for (int j = 0; j < 32; j += 8)
        out[(long)(c0 + ty + j) * ldout + r0 + tx] = tile[tx][ty + j];
}

extern "C" void kernel_launch(void* const* d_in, const int* in_sizes, int n_in,
                              void* d_out, int out_size, void* d_ws, size_t ws_size,
                              hipStream_t stream)
{
    const float* x  = (const float*)d_in[0];
    const float* Wq = (const float*)d_in[1];
    const float* Wk = (const float*)d_in[2];
    const float* Wv = (const float*)d_in[3];
    float* out = (float*)d_out;

    char* ws = (char*)d_ws;
    const long XN = (long)SEQ * DMODEL;     // 8,388,608
    const long WN = (long)DMODEL * DMODEL;  // 1,048,576
    const long SN = (long)SEQ * SEQ;        // 67,108,864

    bf16_t* xb   = (bf16_t*)ws;                              // 16MB
    bf16_t* wcat = (bf16_t*)(ws + XN * 2);                   // 6MB [3072,1024]
    bf16_t* qb   = (bf16_t*)(ws + XN * 2 + WN * 6);          // 16MB compact
    bf16_t* kb   = qb + XN;                                  // 16MB compact
    bf16_t* vb   = qb + 2 * XN;                              // 16MB compact
    bf16_t* Sb   = (bf16_t*)(ws + XN * 2 + WN * 6 + XN * 6); // 128MB
    float*  pvp  = (float*)(ws + XN * 2 + WN * 6 + XN * 6 + SN * 2); // 32MB
    float*  lsum = (float*)(ws + XN * 2 + WN * 6 + XN * 6 + SN * 2 + XN * 4); // 32KB
    bf16_t* vtb  = xb;  // v^T overlays x_bf16 (x dead after QKV GEMM)

    const size_t base_need = (size_t)(XN * 2 + WN * 6 + XN * 6 + SN * 2);
    const bool use_split = ws_size >= base_need + XN * 4 + SEQ * 4;
    if (!use_split) lsum = (float*)(ws + base_need);  // reuse pvp slot

    convert_f32_bf16<<<(int)(XN / 4 / 256), 256, 0, stream>>>(x,  xb, XN);
    convert_f32_bf16<<<(int)(WN / 4 / 256), 256, 0, stream>>>(Wq, wcat,          WN);
    convert_f32_bf16<<<(int)(WN / 4 / 256), 256, 0, stream>>>(Wk, wcat + WN,     WN);
    convert_f32_bf16<<<(int)(WN / 4 / 256), 256, 0, stream>>>(Wv, wcat + 2 * WN, WN);
    zero_f32<<<SEQ / 256, 256, 0, stream>>>(lsum, SEQ);

    dim3 blk(256);
    // qkv = x @ Wcat^T, de-interleaved into compact q|k|v (plane=XN, cshift=10)
    gemm_nt<bf16_t, 0><<<(SEQ / 128) * (3 * DMODEL / 128), blk, 0, stream>>>(
        xb, wcat, qb, qb, nullptr, SEQ, 3 * DMODEL, DMODEL,
        DMODEL, DMODEL, DMODEL, XN, 10, 1.0f);

    // v^T for the PV GEMM (writes over dead x_bf16)
    transpose_bf16<<<dim3(DMODEL / 32, SEQ / 32), blk, 0, stream>>>(
        vb, vtb, SEQ, DMODEL, SEQ);

    // P' = exp2((q@k^T) * scale * log2e), bf16; row sums -> lsum (atomic)
    gemm_nt<bf16_t, 1><<<(SEQ / 128) * (SEQ / 128), blk, 0, stream>>>(
        qb, kb, Sb, Sb, lsum, SEQ, SEQ, DMODEL,
        DMODEL, DMODEL, SEQ, 0, 30, 0.03125f * LOG2E);

    // out = (P' @ v) / l  (PV epilogue applies 1/lsum[row]). Split-K=2 if ws.
    if (use_split) {
        gemm_nt<float, 2><<<2 * (SEQ / 128) * (DMODEL / 128), blk, 0, stream>>>(
            Sb, vtb, out, pvp, lsum, SEQ, DMODEL, SEQ / 2,
            SEQ, SEQ, DMODEL, 0, 30, 1.0f);
        add_f32<<<(int)(XN / 4 / 256), 256, 0, stream>>>(out, pvp, XN);
    } else {
        gemm_nt<float, 2><<<(SEQ / 128) * (DMODEL / 128), blk, 0, stream>>>(
            Sb, vtb, out, out, lsum, SEQ, DMODEL, SEQ,
            SEQ, SEQ, DMODEL, 0, 30, 1.0f);
    }
}